// Round 10
// baseline (399.130 us; speedup 1.0000x reference)
//
#include <hip/hip_runtime.h>
#include <hip/hip_bf16.h>
#include <math.h>
#include <stdint.h>

#define N_NODES 100000
#define N_EDGES 1600000
#define ET (N_EDGES + N_NODES)   // 1,700,000 edges incl. self-loops
#define FDIM 128
#define NK 16
#define EPS 1e-5f
#define SLOPE 0.2f

typedef __attribute__((ext_vector_type(8))) short bf16x8;
typedef __attribute__((ext_vector_type(4))) float f32x4;
typedef __attribute__((ext_vector_type(2))) _Float16 h2;

__device__ inline unsigned pk_bf16(float a, float b) {
    float2 f; f.x = a; f.y = b;
    __hip_bfloat162 t = __float22bfloat162_rn(f);
    return *reinterpret_cast<unsigned*>(&t);
}
__device__ inline h2 as_h2(unsigned u) { return __builtin_bit_cast(h2, u); }
__device__ inline unsigned as_u(h2 v) { return __builtin_bit_cast(unsigned, v); }

// single-instruction lane swizzle (BitMode: xor masks within 32-lane halves)
#define SWZ(X, P) __int_as_float(__builtin_amdgcn_ds_swizzle(__float_as_int(X), (P)))
// DPP lane permutes (VALU-pipe, no LDS latency)
#define DPPF(X, CTRL) __int_as_float(__builtin_amdgcn_mov_dpp(__float_as_int(X), (CTRL), 0xF, 0xF, true))
#define DX1(X) DPPF(X, 0xB1)    // quad_perm [1,0,3,2]  == xor 1
#define DX2(X) DPPF(X, 0x4E)    // quad_perm [2,3,0,1]  == xor 2
#define DR4(X) DPPF(X, 0x124)   // row_ror:4
#define DR8(X) DPPF(X, 0x128)   // row_ror:8
// quad-level broadcasts: within a quad, lane k holds edge-k's weight
#define DB0(X) DPPF(X, 0x00)    // quad_perm [0,0,0,0]
#define DB1(X) DPPF(X, 0x55)    // quad_perm [1,1,1,1]
#define DB2(X) DPPF(X, 0xAA)    // quad_perm [2,2,2,2]
#define DB3(X) DPPF(X, 0xFF)    // quad_perm [3,3,3,3]
// full 64-lane sum into every lane (verified ror-reduce + xor16 + xor32)
#define RED64(S) { S += DX1(S); S += DX2(S); S += DR4(S); S += DR8(S); \
                   S += SWZ(S, 0x401F); S += __shfl_xor(S, 32); }

// exp2 on the transcendental pipe (D = 2^S0)
__device__ inline float exp2_hw(float x) {
    float r;
    asm("v_exp_f32 %0, %1" : "=v"(r) : "v"(x));
    return r;
}

// fused fp16->fp32 multiply-accumulate: ACC += half(U) * W  (1 VALU op)
#define FMAMIX_LO(ACC, U, W) \
    asm("v_fma_mix_f32 %0, %1, %2, %0 op_sel_hi:[1,0,0]" : "+v"(ACC) : "v"(U), "v"(W))
#define FMAMIX_HI(ACC, U, W) \
    asm("v_fma_mix_f32 %0, %1, %2, %0 op_sel:[1,0,0] op_sel_hi:[1,0,0]" : "+v"(ACC) : "v"(U), "v"(W))

// readfirstlane + mask to <2^17: speculative (prefetched) perm entries may be
// garbage; masking keeps the gather offset within +33.5 MB of the xl base
// (inside ws for every base used here).
__device__ inline int rflm(int v) { return __builtin_amdgcn_readfirstlane(v) & 131071; }

// ---------------- CSR build: 2-phase bucket partition ----------------

#define NBKT 196
#define BSH 9                      // 512 nodes / bucket
#define BSTRIDE 10240              // staging stride (mean 8704, sigma 93 -> +16 sigma)
#define P1_EPT 8
#define P1_EPB (256 * P1_EPT)      // 2048 edges / block
#define PART_BLOCKS ((ET + P1_EPB - 1) / P1_EPB)   // 831

// fused: blocks [0, PART_BLOCKS) = edge partition; [PART_BLOCKS, +40) = W swizzle.
__global__ __launch_bounds__(256) void prep_kernel(
        const int* __restrict__ ei, int* __restrict__ gcount,
        int* __restrict__ staging,
        const float* __restrict__ Wp, const float* __restrict__ Wl,
        const float* __restrict__ Wr, ushort* __restrict__ wbp,
        ushort* __restrict__ wbl0, ushort* __restrict__ wbl1) {
    __shared__ int hist[NBKT];
    __shared__ int lofs[NBKT];
    __shared__ int gbase[NBKT];
    __shared__ int s[256];
    __shared__ int spk[P1_EPB];
    __shared__ short sbk[P1_EPB];
    int bid = blockIdx.x;
    int t = threadIdx.x;
    if (bid >= PART_BLOCKS) {
        int bb = bid - PART_BLOCKS;
        const float *W0, *W1; ushort* out; int nt;
        if (bb < 8)       { W0 = Wp; W1 = Wp; out = wbp; nt = bb; }
        else if (bb < 24) { W0 = Wl; W1 = Wr; out = wbl0; nt = bb - 8; }
        else              { W0 = Wl + FDIM * FDIM; W1 = Wr + FDIM * FDIM; out = wbl1; nt = bb - 24; }
        int kk = t >> 6, lane = t & 63;
        int n = nt * 16 + (lane & 15);
        int k0 = kk * 32 + (lane >> 4) * 8;
        const float* W = (n < 128) ? (W0 + n) : (W1 + (n - 128));
        float f[8];
#pragma unroll
        for (int j = 0; j < 8; j++) f[j] = W[(size_t)(k0 + j) * FDIM];
        uint4 u;
        u.x = pk_bf16(f[0], f[1]); u.y = pk_bf16(f[2], f[3]);
        u.z = pk_bf16(f[4], f[5]); u.w = pk_bf16(f[6], f[7]);
        *(uint4*)&out[(size_t)((nt * 4 + kk) * 64 + lane) * 8] = u;
        return;
    }
    if (t < NBKT) hist[t] = 0;
    __syncthreads();
    int e0 = bid * P1_EPB + t;
    int pk[P1_EPT], bk[P1_EPT], rk[P1_EPT];
#pragma unroll
    for (int k = 0; k < P1_EPT; k++) {
        int e = e0 + k * 256;
        bk[k] = -1;
        if (e < ET) {
            int src, dst;
            if (e < N_EDGES) { src = ei[e]; dst = ei[N_EDGES + e]; }
            else             { src = dst = e - N_EDGES; }
            int b = dst >> BSH;
            pk[k] = (src << BSH) | (dst & 511);
            bk[k] = b;
            rk[k] = atomicAdd(&hist[b], 1);
        }
    }
    __syncthreads();
    int v = (t < NBKT) ? hist[t] : 0;
    s[t] = v;
    __syncthreads();
    for (int o = 1; o < 256; o <<= 1) {
        int add = (t >= o) ? s[t - o] : 0;
        __syncthreads();
        s[t] += add;
        __syncthreads();
    }
    if (t < NBKT) {
        lofs[t] = s[t] - v;
        gbase[t] = (v > 0) ? atomicAdd(&gcount[t], v) : 0;
    }
    __syncthreads();
#pragma unroll
    for (int k = 0; k < P1_EPT; k++) {
        if (bk[k] >= 0) {
            int idx = lofs[bk[k]] + rk[k];
            spk[idx] = pk[k];
            sbk[idx] = (short)bk[k];
        }
    }
    __syncthreads();
    int tot = lofs[NBKT - 1] + hist[NBKT - 1];
    for (int i = t; i < tot; i += 256) {
        int b = sbk[i];
        staging[b * BSTRIDE + gbase[b] + (i - lofs[b])] = spk[i];
    }
}

// fused: blocks [0, NBKT) = bucket CSR; [NBKT, +1563) = proj GEMM, and when
// wbl != nullptr also LN + layer-0 GEMM2 in-register.
__global__ __launch_bounds__(256) void csr_projln_kernel(
        const int* __restrict__ staging, const int* __restrict__ gcount,
        int* __restrict__ off, int* __restrict__ perm,
        const float* __restrict__ x, const ushort* __restrict__ wb,
        const float* __restrict__ bp, float* __restrict__ h,
        const ushort* __restrict__ wbl,
        const float* __restrict__ g_, const float* __restrict__ b_,
        const float* __restrict__ bl, const float* __restrict__ br,
        ushort* __restrict__ xlh, ushort* __restrict__ xrh) {
    __shared__ uint4 fragbuf[4 * 272];
    int bid = blockIdx.x;
    int t = threadIdx.x;
    if (bid >= NBKT) {
        int wid = ((bid - NBKT) * 256 + t) >> 6;
        int lane = t & 63;
        if (wid >= N_NODES / 16) return;
        uint4* fb = fragbuf + (t >> 6) * 272;
        int q = lane >> 4, m = lane & 15;
        int row0 = wid * 16;
        const float* xrow = x + (size_t)(row0 + m) * FDIM + q * 32;
#pragma unroll
        for (int p = 0; p < 4; p++) {
            float4 a = *(const float4*)&xrow[p * 8];
            float4 c = *(const float4*)&xrow[p * 8 + 4];
            uint4 u;
            u.x = pk_bf16(a.x, a.y); u.y = pk_bf16(a.z, a.w);
            u.z = pk_bf16(c.x, c.y); u.w = pk_bf16(c.z, c.w);
            fb[q * 68 + p * 17 + m] = u;
        }
        bf16x8 A[4];
#pragma unroll
        for (int kk = 0; kk < 4; kk++)
            A[kk] = *(const bf16x8*)&fb[kk * 68 + q * 17 + m];
        const bf16x8* wbv = (const bf16x8*)wb;
        f32x4 acc[8];
        f32x4 z = {0.f, 0.f, 0.f, 0.f};
#pragma unroll
        for (int nt = 0; nt < 8; nt++) acc[nt] = z;
#pragma unroll
        for (int nt = 0; nt < 8; nt++) {
#pragma unroll
            for (int kk = 0; kk < 4; kk++) {
                bf16x8 B = wbv[(nt * 4 + kk) * 64 + lane];
                acc[nt] = __builtin_amdgcn_mfma_f32_16x16x32_bf16(A[kk], B, acc[nt], 0, 0, 0);
            }
        }
        float hv[8][4];
#pragma unroll
        for (int nt = 0; nt < 8; nt++) {
            int col = nt * 16 + m;
            float bias = bp[col];
#pragma unroll
            for (int r = 0; r < 4; r++) {
                hv[nt][r] = acc[nt][r] + bias;
                h[(size_t)(row0 + q * 4 + r) * FDIM + col] = hv[nt][r];
            }
        }
        if (!wbl) return;
        float gc[8], bcv[8];
#pragma unroll
        for (int nt = 0; nt < 8; nt++) { gc[nt] = g_[nt * 16 + m]; bcv[nt] = b_[nt * 16 + m]; }
        ushort* fbu = (ushort*)fb;
#pragma unroll
        for (int r = 0; r < 4; r++) {
            float s = 0.f, ss = 0.f;
#pragma unroll
            for (int nt = 0; nt < 8; nt++) { s += hv[nt][r]; ss += hv[nt][r] * hv[nt][r]; }
            s += SWZ(s, 0x041F); s += SWZ(s, 0x081F); s += SWZ(s, 0x101F); s += SWZ(s, 0x201F);
            ss += SWZ(ss, 0x041F); ss += SWZ(ss, 0x081F); ss += SWZ(ss, 0x101F); ss += SWZ(ss, 0x201F);
            float mu = s * (1.f / 128.f);
            float rv = rsqrtf(ss * (1.f / 128.f) - mu * mu + EPS);
#pragma unroll
            for (int nt = 0; nt < 8; nt++) {
                float val = (hv[nt][r] - mu) * rv * gc[nt] + bcv[nt];
                ushort us = (ushort)pk_bf16(val, val);
                fbu[(((nt >> 1) * 68 + ((nt & 1) * 2 + (m >> 3)) * 17 + (q * 4 + r)) << 3) + (m & 7)] = us;
            }
        }
        bf16x8 A2[4];
#pragma unroll
        for (int kk = 0; kk < 4; kk++)
            A2[kk] = *(const bf16x8*)&fb[kk * 68 + q * 17 + m];
        const bf16x8* wlv = (const bf16x8*)wbl;
        f32x4 acc2[16];
#pragma unroll
        for (int nt = 0; nt < 16; nt++) acc2[nt] = z;
#pragma unroll
        for (int nt = 0; nt < 16; nt++) {
#pragma unroll
            for (int kk = 0; kk < 4; kk++) {
                bf16x8 B = wlv[(nt * 4 + kk) * 64 + lane];
                acc2[nt] = __builtin_amdgcn_mfma_f32_16x16x32_bf16(A2[kk], B, acc2[nt], 0, 0, 0);
            }
        }
#pragma unroll
        for (int nt = 0; nt < 16; nt++) {
            int col = nt * 16 + m;
            if (nt < 8) {
                float bias = bl[col];
#pragma unroll
                for (int r = 0; r < 4; r++) {
                    _Float16 hf = (_Float16)(acc2[nt][r] + bias);
                    xlh[(size_t)(row0 + q * 4 + r) * FDIM + col] = __builtin_bit_cast(ushort, hf);
                }
            } else {
                int c2 = col - 128;
                float bias = br[c2];
#pragma unroll
                for (int r = 0; r < 4; r++) {
                    _Float16 hf = (_Float16)(acc2[nt][r] + bias);
                    xrh[(size_t)(row0 + q * 4 + r) * FDIM + c2] = __builtin_bit_cast(ushort, hf);
                }
            }
        }
        return;
    }
    // ---- bucket CSR (256 threads) ----
    int* hist = (int*)fragbuf;
    int* cur  = hist + 512;
    int* pr   = cur + 512;
    int* gpre = pr + 256;
    int b = bid;
    hist[t] = 0; hist[t + 256] = 0;
    gpre[t] = (t < NBKT) ? gcount[t] : 0;
    __syncthreads();
    int sz = gcount[b];
    for (int k = t; k < sz; k += 256)
        atomicAdd(&hist[staging[b * BSTRIDE + k] & 511], 1);
    __syncthreads();
    int a0 = hist[2 * t], a1 = hist[2 * t + 1];
    pr[t] = a0 + a1;
    __syncthreads();
    for (int o = 1; o < 256; o <<= 1) {
        int ad = (t >= o) ? pr[t - o] : 0;
        int gd = (t >= o) ? gpre[t - o] : 0;
        __syncthreads();
        pr[t] += ad;
        gpre[t] += gd;
        __syncthreads();
    }
    int base = gpre[b] - sz;
    int pe = pr[t] - (a0 + a1);
    cur[2 * t] = pe;
    cur[2 * t + 1] = pe + a0;
    int n = (b << BSH) + 2 * t;
    if (n < N_NODES)     off[n]     = base + pe;
    if (n + 1 < N_NODES) off[n + 1] = base + pe + a0;
    if (b == 0 && t == 0) off[N_NODES] = ET;
    __syncthreads();
    for (int k = t; k < sz; k += 256) {
        int p = staging[b * BSTRIDE + k];
        int slot = atomicAdd(&cur[p & 511], 1);
        perm[base + slot] = p >> BSH;
    }
}

// ---------------- standalone LN+GEMM2 (fallback only) ----------------

__global__ __launch_bounds__(256) void ln_gemm2_kernel(
        const float* __restrict__ h,
        const float* __restrict__ g, const float* __restrict__ b,
        const ushort* __restrict__ wb, const float* __restrict__ bl,
        const float* __restrict__ br,
        ushort* __restrict__ xlh, ushort* __restrict__ xrh) {
    __shared__ uint4 fragbuf[4 * 272];
    int wid = (blockIdx.x * 256 + threadIdx.x) >> 6;
    int lane = threadIdx.x & 63;
    if (wid >= N_NODES / 16) return;
    uint4* fb = fragbuf + (threadIdx.x >> 6) * 272;
    int q = lane >> 4, m = lane & 15;
    int row0 = wid * 16;
    const float* hrow = h + (size_t)(row0 + m) * FDIM + q * 32;
    float v[32];
#pragma unroll
    for (int i = 0; i < 8; i++) {
        float4 t4 = *(const float4*)&hrow[i * 4];
        v[i * 4 + 0] = t4.x; v[i * 4 + 1] = t4.y; v[i * 4 + 2] = t4.z; v[i * 4 + 3] = t4.w;
    }
    float s = 0.f, ss = 0.f;
#pragma unroll
    for (int i = 0; i < 32; i++) { s += v[i]; ss += v[i] * v[i]; }
    s  += __shfl_xor(s, 16);  s  += __shfl_xor(s, 32);
    ss += __shfl_xor(ss, 16); ss += __shfl_xor(ss, 32);
    float mu = s * (1.f / 128.f);
    float var = ss * (1.f / 128.f) - mu * mu;
    float rv = rsqrtf(var + EPS);
#pragma unroll
    for (int i = 0; i < 8; i++) {
        float4 gv = *(const float4*)&g[q * 32 + i * 4];
        float4 bv = *(const float4*)&b[q * 32 + i * 4];
        v[i * 4 + 0] = (v[i * 4 + 0] - mu) * rv * gv.x + bv.x;
        v[i * 4 + 1] = (v[i * 4 + 1] - mu) * rv * gv.y + bv.y;
        v[i * 4 + 2] = (v[i * 4 + 2] - mu) * rv * gv.z + bv.z;
        v[i * 4 + 3] = (v[i * 4 + 3] - mu) * rv * gv.w + bv.w;
    }
#pragma unroll
    for (int p = 0; p < 4; p++) {
        uint4 u;
        u.x = pk_bf16(v[p * 8 + 0], v[p * 8 + 1]);
        u.y = pk_bf16(v[p * 8 + 2], v[p * 8 + 3]);
        u.z = pk_bf16(v[p * 8 + 4], v[p * 8 + 5]);
        u.w = pk_bf16(v[p * 8 + 6], v[p * 8 + 7]);
        fb[q * 68 + p * 17 + m] = u;
    }
    bf16x8 A[4];
#pragma unroll
    for (int kk = 0; kk < 4; kk++)
        A[kk] = *(const bf16x8*)&fb[kk * 68 + q * 17 + m];
    const bf16x8* wbv = (const bf16x8*)wb;
    f32x4 acc[16];
    f32x4 z = {0.f, 0.f, 0.f, 0.f};
#pragma unroll
    for (int nt = 0; nt < 16; nt++) acc[nt] = z;
#pragma unroll
    for (int nt = 0; nt < 16; nt++) {
#pragma unroll
        for (int kk = 0; kk < 4; kk++) {
            bf16x8 B = wbv[(nt * 4 + kk) * 64 + lane];
            acc[nt] = __builtin_amdgcn_mfma_f32_16x16x32_bf16(A[kk], B, acc[nt], 0, 0, 0);
        }
    }
#pragma unroll
    for (int nt = 0; nt < 16; nt++) {
        int col = nt * 16 + m;
        if (nt < 8) {
            float bias = bl[col];
#pragma unroll
            for (int r = 0; r < 4; r++) {
                _Float16 hf = (_Float16)(acc[nt][r] + bias);
                xlh[(size_t)(row0 + q * 4 + r) * FDIM + col] = __builtin_bit_cast(ushort, hf);
            }
        } else {
            int c2 = col - 128;
            float bias = br[c2];
#pragma unroll
            for (int r = 0; r < 4; r++) {
                _Float16 hf = (_Float16)(acc[nt][r] + bias);
                xrh[(size_t)(row0 + q * 4 + r) * FDIM + c2] = __builtin_bit_cast(ushort, hf);
            }
        }
    }
}

// ---------------- GATv2 aggregation: 512 threads, 16 nodes / block ---------
// Gather path unchanged (memory-ceiling-pinned). Two optional fused epilogues:
//  * Wc != nullptr  (layer 1): classification head. Stride-4 group assignment
//    makes sh reads 4-distinct-bank and WcS reads 2-way (free) — fixes R9's
//    3.2M bank conflicts.
//  * wbl != nullptr (layer 0): LN + layer-1 GEMM2 from the fresh h1 rows —
//    the block owns a full 16-row MFMA A-fragment (8 waves x 2 nodes).
//    Writes xl1/xr1 (SEPARATE buffers: gat still gathers from xl0).

__global__ __launch_bounds__(512) void gat_agg_kernel(
        const unsigned* __restrict__ xlp, const unsigned* __restrict__ xrp,
        const int* __restrict__ off, const int* __restrict__ perm,
        const float* __restrict__ att, const float* __restrict__ gb,
        float* __restrict__ h,
        const float* __restrict__ Wc, const float* __restrict__ bc,
        float* __restrict__ out_cls,
        const ushort* __restrict__ wbl,
        const float* __restrict__ lgp, const float* __restrict__ lbp,
        const float* __restrict__ bl1, const float* __restrict__ br1,
        ushort* __restrict__ xl1, ushort* __restrict__ xr1) {
    __shared__ float WcS[FDIM * NK];    // 8 KB; L0 epilogue aliases as A-frag buf
    __shared__ float hbuf[8 * 256];     // 8 KB; head only
    bool dofinal = (Wc != nullptr);
    if (dofinal) {
        for (int i = threadIdx.x; i < FDIM * NK; i += 512) WcS[i] = Wc[i];
        __syncthreads();   // block-uniform
    }
    int wave = (blockIdx.x * 512 + threadIdx.x) >> 6;
    unsigned lane = threadIdx.x & 63;
    int iA = wave * 2;
    int iB = iA + 1;   // grid covers exactly N/2 waves
    int2 oA = *(const int2*)&off[iA];
    int eB2 = off[iB + 1];
    h2 xrvA = as_h2(xrp[(unsigned)iA * 64u + lane]);
    h2 xrvB = as_h2(xrp[(unsigned)iB * 64u + lane]);
    const float2 hidA = *(const float2*)&h[(size_t)iA * FDIM + lane * 2];
    const float2 hidB = *(const float2*)&h[(size_t)iB * FDIM + lane * 2];
    const float2 gbv = *(const float2*)&gb[lane * 2];
    float2 attf = *(const float2*)&att[lane * 2];
    h2 attp; attp[0] = (_Float16)(attf.x * 1.44269504f);
    attp[1] = (_Float16)(attf.y * 1.44269504f);
    const h2 c06 = {(_Float16)0.6f, (_Float16)0.6f};
    const h2 c04 = {(_Float16)0.4f, (_Float16)0.4f};
    bool b0 = lane & 1, b1 = lane & 2;
    int begA = __builtin_amdgcn_readfirstlane(oA.x);
    int endA = __builtin_amdgcn_readfirstlane(oA.y);
    int begB = endA;
    int endB = __builtin_amdgcn_readfirstlane(eB2);
    const char* xlB_ = (const char*)xlp;
    unsigned laneB = lane << 2;

#define GLD(J) (*(const unsigned*)(xlB_ + ((unsigned)(J) * 256u + laneB)))

#define EDGE_PARTIAL(XRV, U, T)                                     \
    {                                                               \
        h2 mm = as_h2(U) + XRV;                                     \
        h2 am = as_h2(as_u(mm) & 0x7FFF7FFFu);                      \
        h2 sv = am * c04 + mm * c06;                                \
        T = __builtin_amdgcn_fdot2(sv, attp, 0.f, false);           \
    }

#define COMPUTE4(S, U0, U1, U2, U3)                                 \
    {                                                               \
        float t0, t1, t2, t3;                                       \
        EDGE_PARTIAL(xrv##S, U0, t0);                               \
        EDGE_PARTIAL(xrv##S, U1, t1);                               \
        EDGE_PARTIAL(xrv##S, U2, t2);                               \
        EDGE_PARTIAL(xrv##S, U3, t3);                               \
        float u   = b0 ? t1 : t0;                                   \
        float uu2 = b0 ? t0 : t1;                                   \
        u += DX1(uu2);                                              \
        float vv  = b0 ? t3 : t2;                                   \
        float vv2 = b0 ? t2 : t3;                                   \
        vv += DX1(vv2);                                             \
        float ww  = b1 ? vv : u;                                    \
        float ww2 = b1 ? u : vv;                                    \
        ww += DX2(ww2);                                             \
        ww += DR4(ww);                                              \
        ww += DR8(ww);                                              \
        float ew = exp2_hw(ww);                                     \
        dloc##S += ew;                                              \
        float w0 = DB0(ew);                                         \
        float w1 = DB1(ew);                                         \
        float w2 = DB2(ew);                                         \
        float w3 = DB3(ew);                                         \
        FMAMIX_LO(accx##S, U0, w0); FMAMIX_HI(accy##S, U0, w0);     \
        FMAMIX_LO(accx##S, U1, w1); FMAMIX_HI(accy##S, U1, w1);     \
        FMAMIX_LO(accx##S, U2, w2); FMAMIX_HI(accy##S, U2, w2);     \
        FMAMIX_LO(accx##S, U3, w3); FMAMIX_HI(accy##S, U3, w3);     \
    }

#define TAIL1(S, U)                                                 \
    {                                                               \
        float tt;                                                   \
        EDGE_PARTIAL(xrv##S, U, tt);                                \
        tt += DX1(tt);                                              \
        tt += DX2(tt);                                              \
        tt += DR4(tt);                                              \
        tt += DR8(tt);                                              \
        float w = exp2_hw(tt);                                      \
        if ((lane & 3) == 0) dloc##S += w;                          \
        FMAMIX_LO(accx##S, U, w); FMAMIX_HI(accy##S, U, w);         \
    }

    int nbA = (endA - begA) >> 2, tlA = (endA - begA) & 3;
    int nbB = (endB - begB) >> 2, tlB = (endB - begB) & 3;
    float accxA = 0.f, accyA = 0.f, dlocA = 0.f;
    float accxB = 0.f, accyB = 0.f, dlocB = 0.f;
    unsigned c0A, c1A, c2A, c3A, d0A, d1A, d2A, d3A; int4 p2A;
    unsigned c0B, c1B, c2B, c3B, d0B, d1B, d2B, d3B; int4 p2B;
    unsigned t0A = 0, t1A = 0, t2A = 0, t0B = 0, t1B = 0, t2B = 0;
    int4 p0A, p1A, ptA, p0B, p1B, ptB;

    if (nbA > 0) {
        __builtin_memcpy(&p0A, perm + begA, 16);
        __builtin_memcpy(&p1A, perm + begA + 4, 16);
        __builtin_memcpy(&p2A, perm + begA + 8, 16);
    }
    if (tlA > 0) __builtin_memcpy(&ptA, perm + begA + 4 * nbA, 16);
    if (nbB > 0) {
        __builtin_memcpy(&p0B, perm + begB, 16);
        __builtin_memcpy(&p1B, perm + begB + 4, 16);
        __builtin_memcpy(&p2B, perm + begB + 8, 16);
    }
    if (tlB > 0) __builtin_memcpy(&ptB, perm + begB + 4 * nbB, 16);
    if (nbA > 0) {
        c0A = GLD(rflm(p0A.x)); c1A = GLD(rflm(p0A.y)); c2A = GLD(rflm(p0A.z)); c3A = GLD(rflm(p0A.w));
        d0A = GLD(rflm(p1A.x)); d1A = GLD(rflm(p1A.y)); d2A = GLD(rflm(p1A.z)); d3A = GLD(rflm(p1A.w));
    }
    if (nbB > 0) {
        c0B = GLD(rflm(p0B.x)); c1B = GLD(rflm(p0B.y)); c2B = GLD(rflm(p0B.z)); c3B = GLD(rflm(p0B.w));
        d0B = GLD(rflm(p1B.x)); d1B = GLD(rflm(p1B.y)); d2B = GLD(rflm(p1B.z)); d3B = GLD(rflm(p1B.w));
    }
    if (tlA > 0) {
        t0A = GLD(rflm(ptA.x));
        if (tlA > 1) t1A = GLD(rflm(ptA.y));
        if (tlA > 2) t2A = GLD(rflm(ptA.z));
    }
    if (tlB > 0) {
        t0B = GLD(rflm(ptB.x));
        if (tlB > 1) t1B = GLD(rflm(ptB.y));
        if (tlB > 2) t2B = GLD(rflm(ptB.z));
    }

    int blkA = 0, blkB = 0;
    while (blkA + 2 < nbA && blkB + 2 < nbB) {
        unsigned e0 = GLD(rflm(p2A.x)), e1 = GLD(rflm(p2A.y));
        unsigned e2 = GLD(rflm(p2A.z)), e3 = GLD(rflm(p2A.w));
        unsigned f0 = GLD(rflm(p2B.x)), f1 = GLD(rflm(p2B.y));
        unsigned f2 = GLD(rflm(p2B.z)), f3 = GLD(rflm(p2B.w));
        __builtin_memcpy(&p2A, perm + begA + 4 * blkA + 12, 16);
        __builtin_memcpy(&p2B, perm + begB + 4 * blkB + 12, 16);
        COMPUTE4(A, c0A, c1A, c2A, c3A);
        c0A = d0A; c1A = d1A; c2A = d2A; c3A = d3A;
        d0A = e0; d1A = e1; d2A = e2; d3A = e3;
        COMPUTE4(B, c0B, c1B, c2B, c3B);
        c0B = d0B; c1B = d1B; c2B = d2B; c3B = d3B;
        d0B = f0; d1B = f1; d2B = f2; d3B = f3;
        ++blkA; ++blkB;
    }
    for (; blkA + 2 < nbA; ++blkA) {
        unsigned e0 = GLD(rflm(p2A.x)), e1 = GLD(rflm(p2A.y));
        unsigned e2 = GLD(rflm(p2A.z)), e3 = GLD(rflm(p2A.w));
        __builtin_memcpy(&p2A, perm + begA + 4 * blkA + 12, 16);
        COMPUTE4(A, c0A, c1A, c2A, c3A);
        c0A = d0A; c1A = d1A; c2A = d2A; c3A = d3A;
        d0A = e0; d1A = e1; d2A = e2; d3A = e3;
    }
    for (; blkB + 2 < nbB; ++blkB) {
        unsigned f0 = GLD(rflm(p2B.x)), f1 = GLD(rflm(p2B.y));
        unsigned f2 = GLD(rflm(p2B.z)), f3 = GLD(rflm(p2B.w));
        __builtin_memcpy(&p2B, perm + begB + 4 * blkB + 12, 16);
        COMPUTE4(B, c0B, c1B, c2B, c3B);
        c0B = d0B; c1B = d1B; c2B = d2B; c3B = d3B;
        d0B = f0; d1B = f1; d2B = f2; d3B = f3;
    }
    if (nbA >= 2) {
        COMPUTE4(A, c0A, c1A, c2A, c3A);
        c0A = d0A; c1A = d1A; c2A = d2A; c3A = d3A;
    }
    if (nbB >= 2) {
        COMPUTE4(B, c0B, c1B, c2B, c3B);
        c0B = d0B; c1B = d1B; c2B = d2B; c3B = d3B;
    }
    if (nbA >= 1) COMPUTE4(A, c0A, c1A, c2A, c3A);
    if (nbB >= 1) COMPUTE4(B, c0B, c1B, c2B, c3B);
    if (tlA > 0) {
        TAIL1(A, t0A);
        if (tlA > 1) TAIL1(A, t1A);
        if (tlA > 2) TAIL1(A, t2A);
    }
    if (tlB > 0) {
        TAIL1(B, t0B);
        if (tlB > 1) TAIL1(B, t1B);
        if (tlB > 2) TAIL1(B, t2B);
    }
#undef EDGE_PARTIAL
#undef COMPUTE4
#undef TAIL1
#undef GLD

    float denA = dlocA + DX1(dlocA);
    denA += DX2(denA);
    float invA = 1.f / denA;
    float2 resA;
    resA.x = fmaxf(accxA * invA + gbv.x, 0.f) + hidA.x;
    resA.y = fmaxf(accyA * invA + gbv.y, 0.f) + hidA.y;
    *(float2*)&h[(size_t)iA * FDIM + lane * 2] = resA;
    float denB = dlocB + DX1(dlocB);
    denB += DX2(denB);
    float invB = 1.f / denB;
    float2 resB;
    resB.x = fmaxf(accxB * invB + gbv.x, 0.f) + hidB.x;
    resB.y = fmaxf(accyB * invB + gbv.y, 0.f) + hidB.y;
    *(float2*)&h[(size_t)iB * FDIM + lane * 2] = resB;

    if (dofinal) {
        // classification from fresh rows; stride-4 groups: sh reads hit 4
        // distinct banks, WcS reads 2-way (free).
        float* sh = hbuf + (threadIdx.x >> 6) * 256;
        sh[lane * 2]       = resA.x; sh[lane * 2 + 1]       = resA.y;
        sh[128 + lane * 2] = resB.x; sh[128 + lane * 2 + 1] = resB.y;
        int k = lane & 15, g = lane >> 4;
        float pA = 0.f, pB = 0.f;
#pragma unroll 8
        for (int i = 0; i < 32; ++i) {
            int c = 4 * i + g;
            float wv = WcS[c * NK + k];
            pA = fmaf(sh[c], wv, pA);
            pB = fmaf(sh[128 + c], wv, pB);
        }
        pA += SWZ(pA, 0x401F);
        pB += SWZ(pB, 0x401F);
        pA += __shfl_xor(pA, 32);
        pB += __shfl_xor(pB, 32);
        if (g == 0) {
            float bk = bc[k];
            out_cls[(size_t)iA * NK + k] = pA + bk;
            out_cls[(size_t)iB * NK + k] = pB + bk;
        }
    }

    if (xl1) {
        // ---- fused LN + layer-1 GEMM2 from the block's 16 fresh rows ----
        float sA = resA.x + resA.y, qsA = resA.x * resA.x + resA.y * resA.y;
        float sB = resB.x + resB.y, qsB = resB.x * resB.x + resB.y * resB.y;
        RED64(sA); RED64(qsA); RED64(sB); RED64(qsB);
        float muA = sA * (1.f / 128.f);
        float rvA = rsqrtf(qsA * (1.f / 128.f) - muA * muA + EPS);
        float muB = sB * (1.f / 128.f);
        float rvB = rsqrtf(qsB * (1.f / 128.f) - muB * muB + EPS);
        float2 lgv = *(const float2*)&lgp[lane * 2];
        float2 lbv = *(const float2*)&lbp[lane * 2];
        // A-fragment layout write: col c=2*lane -> kk=c>>5, p=(c>>3)&3, j=(c>>1)&3
        unsigned* fb32 = (unsigned*)WcS;
        int w = threadIdx.x >> 6;
        int fbase = ((int)(lane >> 4) * 68 + (int)((lane >> 2) & 3) * 17) * 4 + (int)(lane & 3);
        fb32[fbase + (2 * w) * 4] =
            pk_bf16((resA.x - muA) * rvA * lgv.x + lbv.x,
                    (resA.y - muA) * rvA * lgv.y + lbv.y);
        fb32[fbase + (2 * w + 1) * 4] =
            pk_bf16((resB.x - muB) * rvB * lgv.x + lbv.x,
                    (resB.y - muB) * rvB * lgv.y + lbv.y);
        __syncthreads();   // block-uniform (xl1 flag uniform, no early exits)
        const uint4* fbq = (const uint4*)WcS;
        int q = lane >> 4, m = lane & 15;
        bf16x8 A2[4];
#pragma unroll
        for (int kk = 0; kk < 4; kk++)
            A2[kk] = *(const bf16x8*)&fbq[kk * 68 + q * 17 + m];
        const bf16x8* wlv = (const bf16x8*)wbl;
        int row0 = blockIdx.x * 16;
        f32x4 z = {0.f, 0.f, 0.f, 0.f};
#pragma unroll
        for (int tt = 0; tt < 2; ++tt) {
            int nt = 2 * w + tt;
            f32x4 acc2 = z;
#pragma unroll
            for (int kk = 0; kk < 4; kk++)
                acc2 = __builtin_amdgcn_mfma_f32_16x16x32_bf16(
                    A2[kk], wlv[(nt * 4 + kk) * 64 + lane], acc2, 0, 0, 0);
            int col = nt * 16 + m;
            if (nt < 8) {
                float bias = bl1[col];
#pragma unroll
                for (int r = 0; r < 4; r++) {
                    _Float16 hf = (_Float16)(acc2[r] + bias);
                    xl1[(size_t)(row0 + q * 4 + r) * FDIM + col] = __builtin_bit_cast(ushort, hf);
                }
            } else {
                int c2 = col - 128;
                float bias = br1[c2];
#pragma unroll
                for (int r = 0; r < 4; r++) {
                    _Float16 hf = (_Float16)(acc2[r] + bias);
                    xr1[(size_t)(row0 + q * 4 + r) * FDIM + c2] = __builtin_bit_cast(ushort, hf);
                }
            }
        }
    }
}

// ---------------- launch ----------------

extern "C" void kernel_launch(void* const* d_in, const int* in_sizes, int n_in,
                              void* d_out, int out_size, void* d_ws, size_t ws_size,
                              hipStream_t stream) {
    const float* x    = (const float*)d_in[0];
    const int*   ei   = (const int*)  d_in[1];
    const float* Wp   = (const float*)d_in[2];
    const float* bp   = (const float*)d_in[3];
    const float* ln_g = (const float*)d_in[4];
    const float* ln_b = (const float*)d_in[5];
    const float* Wl   = (const float*)d_in[6];
    const float* bl   = (const float*)d_in[7];
    const float* Wr   = (const float*)d_in[8];
    const float* br   = (const float*)d_in[9];
    const float* att  = (const float*)d_in[10];
    const float* gb   = (const float*)d_in[11];
    const float* Wc   = (const float*)d_in[12];
    const float* bc   = (const float*)d_in[13];

    float* out_cls = (float*)d_out;
    float* h = out_cls + (size_t)N_NODES * NK;   // second output region doubles as h buffer

    char* w = (char*)d_ws;
    int* off    = (int*)w; w += (size_t)(N_NODES + 1) * sizeof(int);
    int* gcount = (int*)w; w += 256 * sizeof(int);
    int* perm   = (int*)w; w += (size_t)ET * sizeof(int);
    uintptr_t a = ((uintptr_t)w + 255) & ~(uintptr_t)255;
    ushort* xlh = (ushort*)a;                             // [N][128] fp16
    ushort* xrh = xlh + (size_t)N_NODES * FDIM;           // [N][128] fp16
    ushort* wbp = xrh + (size_t)N_NODES * FDIM;             // proj W swizzled (32 KB)
    ushort* wbl0 = wbp + 8 * 4 * 64 * 8;                    // layer0 Wl|Wr (64 KB)
    ushort* wbl1 = wbl0 + 16 * 4 * 64 * 8;                  // layer1
    char* wend = (char*)(wbl1 + 16 * 4 * 64 * 8);
    size_t base_need = (size_t)(wend - (char*)d_ws);
    size_t stag_sz = (size_t)NBKT * BSTRIDE * sizeof(int);
    size_t xlr1_sz = (size_t)2 * N_NODES * FDIM * sizeof(ushort);
    bool roomy  = (ws_size >= base_need + stag_sz);
    bool roomy2 = (ws_size >= base_need + stag_sz + xlr1_sz);
    int* staging = roomy ? (int*)wend : (int*)xlh;
    ushort* xlh1 = roomy2 ? (ushort*)((char*)wend + stag_sz) : nullptr;
    ushort* xrh1 = roomy2 ? xlh1 + (size_t)N_NODES * FDIM : nullptr;

    // CSR by dst (rebuilt every call — ws is re-poisoned)
    hipMemsetAsync(gcount, 0, NBKT * sizeof(int), stream);
    prep_kernel<<<PART_BLOCKS + 40, 256, 0, stream>>>(
        ei, gcount, staging, Wp, Wl, Wr, wbp, wbl0, wbl1);
    const int gw = (N_NODES / 16 + 3) / 4;   // 1563 proj blocks
    csr_projln_kernel<<<NBKT + gw, 256, 0, stream>>>(
        staging, gcount, off, perm, x, wbp, bp, h,
        roomy ? wbl0 : (const ushort*)nullptr,
        ln_g, ln_b, bl, br, xlh, xrh);
    if (!roomy)
        ln_gemm2_kernel<<<gw, 256, 0, stream>>>(
            h, ln_g, ln_b, wbl0, bl, br, xlh, xrh);

    // layer 0 aggregation; when roomy2, fused LN + layer-1 GEMM2 epilogue
    gat_agg_kernel<<<N_NODES / 16, 512, 0, stream>>>(
        (const unsigned*)xlh, (const unsigned*)xrh, off, perm,
        att, gb, h, nullptr, nullptr, nullptr,
        roomy2 ? wbl1 : (const ushort*)nullptr,
        ln_g + FDIM, ln_b + FDIM, bl + FDIM, br + FDIM, xlh1, xrh1);
    if (!roomy2)
        ln_gemm2_kernel<<<gw, 256, 0, stream>>>(
            h, ln_g + FDIM, ln_b + FDIM, wbl1, bl + FDIM, br + FDIM, xlh, xrh);
    const ushort* xl_1 = roomy2 ? xlh1 : xlh;
    const ushort* xr_1 = roomy2 ? xrh1 : xrh;
    // layer 1 aggregation with fused classification head
    gat_agg_kernel<<<N_NODES / 16, 512, 0, stream>>>(
        (const unsigned*)xl_1, (const unsigned*)xr_1, off, perm,
        att + FDIM, gb + FDIM, h, Wc, bc, out_cls,
        nullptr, nullptr, nullptr, nullptr, nullptr, nullptr, nullptr);
}

// Round 14
// 390.599 us; speedup vs baseline: 1.0218x; 1.0218x over previous
//
#include <hip/hip_runtime.h>
#include <hip/hip_bf16.h>
#include <math.h>
#include <stdint.h>

#define N_NODES 100000
#define N_EDGES 1600000
#define ET (N_EDGES + N_NODES)   // 1,700,000 edges incl. self-loops
#define FDIM 128
#define NK 16
#define EPS 1e-5f
#define SLOPE 0.2f

typedef __attribute__((ext_vector_type(8))) short bf16x8;
typedef __attribute__((ext_vector_type(4))) float f32x4;
typedef __attribute__((ext_vector_type(2))) _Float16 h2;

__device__ inline unsigned pk_bf16(float a, float b) {
    float2 f; f.x = a; f.y = b;
    __hip_bfloat162 t = __float22bfloat162_rn(f);
    return *reinterpret_cast<unsigned*>(&t);
}
__device__ inline h2 as_h2(unsigned u) { return __builtin_bit_cast(h2, u); }
__device__ inline unsigned as_u(h2 v) { return __builtin_bit_cast(unsigned, v); }

// single-instruction lane swizzle (BitMode: xor masks within 32-lane halves)
#define SWZ(X, P) __int_as_float(__builtin_amdgcn_ds_swizzle(__float_as_int(X), (P)))
// DPP lane permutes (VALU-pipe, no LDS latency)
#define DPPF(X, CTRL) __int_as_float(__builtin_amdgcn_mov_dpp(__float_as_int(X), (CTRL), 0xF, 0xF, true))
#define DX1(X) DPPF(X, 0xB1)    // quad_perm [1,0,3,2]  == xor 1
#define DX2(X) DPPF(X, 0x4E)    // quad_perm [2,3,0,1]  == xor 2
#define DR4(X) DPPF(X, 0x124)   // row_ror:4
#define DR8(X) DPPF(X, 0x128)   // row_ror:8
// quad-level broadcasts: within a quad, lane k holds edge-k's weight
#define DB0(X) DPPF(X, 0x00)    // quad_perm [0,0,0,0]
#define DB1(X) DPPF(X, 0x55)    // quad_perm [1,1,1,1]
#define DB2(X) DPPF(X, 0xAA)    // quad_perm [2,2,2,2]
#define DB3(X) DPPF(X, 0xFF)    // quad_perm [3,3,3,3]

// exp2 on the transcendental pipe (D = 2^S0)
__device__ inline float exp2_hw(float x) {
    float r;
    asm("v_exp_f32 %0, %1" : "=v"(r) : "v"(x));
    return r;
}

// fused fp16->fp32 multiply-accumulate: ACC += half(U) * W  (1 VALU op)
#define FMAMIX_LO(ACC, U, W) \
    asm("v_fma_mix_f32 %0, %1, %2, %0 op_sel_hi:[1,0,0]" : "+v"(ACC) : "v"(U), "v"(W))
#define FMAMIX_HI(ACC, U, W) \
    asm("v_fma_mix_f32 %0, %1, %2, %0 op_sel:[1,0,0] op_sel_hi:[1,0,0]" : "+v"(ACC) : "v"(U), "v"(W))

// readfirstlane + mask to <2^17: speculative (prefetched) perm entries may be
// garbage; masking keeps the gather offset inside the workspace (<34 MB).
__device__ inline int rflm(int v) { return __builtin_amdgcn_readfirstlane(v) & 131071; }

// ---------------- CSR build: 2-phase bucket partition ----------------

#define NBKT 196
#define BSH 9                      // 512 nodes / bucket
#define BSTRIDE 10240              // staging stride (mean 8704, sigma 93 -> +16 sigma)
#define P1_EPT 8
#define P1_EPB (256 * P1_EPT)      // 2048 edges / block
#define PART_BLOCKS ((ET + P1_EPB - 1) / P1_EPB)   // 831

// fused: blocks [0, PART_BLOCKS) = edge partition; [PART_BLOCKS, +40) = W swizzle.
__global__ __launch_bounds__(256) void prep_kernel(
        const int* __restrict__ ei, int* __restrict__ gcount,
        int* __restrict__ staging,
        const float* __restrict__ Wp, const float* __restrict__ Wl,
        const float* __restrict__ Wr, ushort* __restrict__ wbp,
        ushort* __restrict__ wbl0, ushort* __restrict__ wbl1) {
    __shared__ int hist[NBKT];
    __shared__ int lofs[NBKT];
    __shared__ int gbase[NBKT];
    __shared__ int s[256];
    __shared__ int spk[P1_EPB];
    __shared__ short sbk[P1_EPB];
    int bid = blockIdx.x;
    int t = threadIdx.x;
    if (bid >= PART_BLOCKS) {
        int bb = bid - PART_BLOCKS;
        const float *W0, *W1; ushort* out; int nt;
        if (bb < 8)       { W0 = Wp; W1 = Wp; out = wbp; nt = bb; }
        else if (bb < 24) { W0 = Wl; W1 = Wr; out = wbl0; nt = bb - 8; }
        else              { W0 = Wl + FDIM * FDIM; W1 = Wr + FDIM * FDIM; out = wbl1; nt = bb - 24; }
        int kk = t >> 6, lane = t & 63;
        int n = nt * 16 + (lane & 15);
        int k0 = kk * 32 + (lane >> 4) * 8;
        const float* W = (n < 128) ? (W0 + n) : (W1 + (n - 128));
        float f[8];
#pragma unroll
        for (int j = 0; j < 8; j++) f[j] = W[(size_t)(k0 + j) * FDIM];
        uint4 u;
        u.x = pk_bf16(f[0], f[1]); u.y = pk_bf16(f[2], f[3]);
        u.z = pk_bf16(f[4], f[5]); u.w = pk_bf16(f[6], f[7]);
        *(uint4*)&out[(size_t)((nt * 4 + kk) * 64 + lane) * 8] = u;
        return;
    }
    if (t < NBKT) hist[t] = 0;
    __syncthreads();
    int e0 = bid * P1_EPB + t;
    int pk[P1_EPT], bk[P1_EPT], rk[P1_EPT];
#pragma unroll
    for (int k = 0; k < P1_EPT; k++) {
        int e = e0 + k * 256;
        bk[k] = -1;
        if (e < ET) {
            int src, dst;
            if (e < N_EDGES) { src = ei[e]; dst = ei[N_EDGES + e]; }
            else             { src = dst = e - N_EDGES; }
            int b = dst >> BSH;
            pk[k] = (src << BSH) | (dst & 511);
            bk[k] = b;
            rk[k] = atomicAdd(&hist[b], 1);
        }
    }
    __syncthreads();
    int v = (t < NBKT) ? hist[t] : 0;
    s[t] = v;
    __syncthreads();
    for (int o = 1; o < 256; o <<= 1) {
        int add = (t >= o) ? s[t - o] : 0;
        __syncthreads();
        s[t] += add;
        __syncthreads();
    }
    if (t < NBKT) {
        lofs[t] = s[t] - v;
        gbase[t] = (v > 0) ? atomicAdd(&gcount[t], v) : 0;
    }
    __syncthreads();
#pragma unroll
    for (int k = 0; k < P1_EPT; k++) {
        if (bk[k] >= 0) {
            int idx = lofs[bk[k]] + rk[k];
            spk[idx] = pk[k];
            sbk[idx] = (short)bk[k];
        }
    }
    __syncthreads();
    int tot = lofs[NBKT - 1] + hist[NBKT - 1];
    for (int i = t; i < tot; i += 256) {
        int b = sbk[i];
        staging[b * BSTRIDE + gbase[b] + (i - lofs[b])] = spk[i];
    }
}

// fused: blocks [0, NBKT) = bucket CSR; [NBKT, +1563) = proj GEMM, and when
// wbl != nullptr also LN + layer-0 GEMM2 in-register.
__global__ __launch_bounds__(256) void csr_projln_kernel(
        const int* __restrict__ staging, const int* __restrict__ gcount,
        int* __restrict__ off, int* __restrict__ perm,
        const float* __restrict__ x, const ushort* __restrict__ wb,
        const float* __restrict__ bp, float* __restrict__ h,
        const ushort* __restrict__ wbl,
        const float* __restrict__ g_, const float* __restrict__ b_,
        const float* __restrict__ bl, const float* __restrict__ br,
        ushort* __restrict__ xlh, ushort* __restrict__ xrh) {
    __shared__ uint4 fragbuf[4 * 272];
    int bid = blockIdx.x;
    int t = threadIdx.x;
    if (bid >= NBKT) {
        int wid = ((bid - NBKT) * 256 + t) >> 6;
        int lane = t & 63;
        if (wid >= N_NODES / 16) return;
        uint4* fb = fragbuf + (t >> 6) * 272;
        int q = lane >> 4, m = lane & 15;
        int row0 = wid * 16;
        const float* xrow = x + (size_t)(row0 + m) * FDIM + q * 32;
#pragma unroll
        for (int p = 0; p < 4; p++) {
            float4 a = *(const float4*)&xrow[p * 8];
            float4 c = *(const float4*)&xrow[p * 8 + 4];
            uint4 u;
            u.x = pk_bf16(a.x, a.y); u.y = pk_bf16(a.z, a.w);
            u.z = pk_bf16(c.x, c.y); u.w = pk_bf16(c.z, c.w);
            fb[q * 68 + p * 17 + m] = u;
        }
        bf16x8 A[4];
#pragma unroll
        for (int kk = 0; kk < 4; kk++)
            A[kk] = *(const bf16x8*)&fb[kk * 68 + q * 17 + m];
        const bf16x8* wbv = (const bf16x8*)wb;
        f32x4 acc[8];
        f32x4 z = {0.f, 0.f, 0.f, 0.f};
#pragma unroll
        for (int nt = 0; nt < 8; nt++) acc[nt] = z;
#pragma unroll
        for (int nt = 0; nt < 8; nt++) {
#pragma unroll
            for (int kk = 0; kk < 4; kk++) {
                bf16x8 B = wbv[(nt * 4 + kk) * 64 + lane];
                acc[nt] = __builtin_amdgcn_mfma_f32_16x16x32_bf16(A[kk], B, acc[nt], 0, 0, 0);
            }
        }
        float hv[8][4];
#pragma unroll
        for (int nt = 0; nt < 8; nt++) {
            int col = nt * 16 + m;
            float bias = bp[col];
#pragma unroll
            for (int r = 0; r < 4; r++) {
                hv[nt][r] = acc[nt][r] + bias;
                h[(size_t)(row0 + q * 4 + r) * FDIM + col] = hv[nt][r];
            }
        }
        if (!wbl) return;
        float gc[8], bcv[8];
#pragma unroll
        for (int nt = 0; nt < 8; nt++) { gc[nt] = g_[nt * 16 + m]; bcv[nt] = b_[nt * 16 + m]; }
        ushort* fbu = (ushort*)fb;
#pragma unroll
        for (int r = 0; r < 4; r++) {
            float s = 0.f, ss = 0.f;
#pragma unroll
            for (int nt = 0; nt < 8; nt++) { s += hv[nt][r]; ss += hv[nt][r] * hv[nt][r]; }
            s += SWZ(s, 0x041F); s += SWZ(s, 0x081F); s += SWZ(s, 0x101F); s += SWZ(s, 0x201F);
            ss += SWZ(ss, 0x041F); ss += SWZ(ss, 0x081F); ss += SWZ(ss, 0x101F); ss += SWZ(ss, 0x201F);
            float mu = s * (1.f / 128.f);
            float rv = rsqrtf(ss * (1.f / 128.f) - mu * mu + EPS);
#pragma unroll
            for (int nt = 0; nt < 8; nt++) {
                float val = (hv[nt][r] - mu) * rv * gc[nt] + bcv[nt];
                ushort us = (ushort)pk_bf16(val, val);
                fbu[(((nt >> 1) * 68 + ((nt & 1) * 2 + (m >> 3)) * 17 + (q * 4 + r)) << 3) + (m & 7)] = us;
            }
        }
        bf16x8 A2[4];
#pragma unroll
        for (int kk = 0; kk < 4; kk++)
            A2[kk] = *(const bf16x8*)&fb[kk * 68 + q * 17 + m];
        const bf16x8* wlv = (const bf16x8*)wbl;
        f32x4 acc2[16];
#pragma unroll
        for (int nt = 0; nt < 16; nt++) acc2[nt] = z;
#pragma unroll
        for (int nt = 0; nt < 16; nt++) {
#pragma unroll
            for (int kk = 0; kk < 4; kk++) {
                bf16x8 B = wlv[(nt * 4 + kk) * 64 + lane];
                acc2[nt] = __builtin_amdgcn_mfma_f32_16x16x32_bf16(A2[kk], B, acc2[nt], 0, 0, 0);
            }
        }
#pragma unroll
        for (int nt = 0; nt < 16; nt++) {
            int col = nt * 16 + m;
            if (nt < 8) {
                float bias = bl[col];
#pragma unroll
                for (int r = 0; r < 4; r++) {
                    _Float16 hf = (_Float16)(acc2[nt][r] + bias);
                    xlh[(size_t)(row0 + q * 4 + r) * FDIM + col] = __builtin_bit_cast(ushort, hf);
                }
            } else {
                int c2 = col - 128;
                float bias = br[c2];
#pragma unroll
                for (int r = 0; r < 4; r++) {
                    _Float16 hf = (_Float16)(acc2[nt][r] + bias);
                    xrh[(size_t)(row0 + q * 4 + r) * FDIM + c2] = __builtin_bit_cast(ushort, hf);
                }
            }
        }
        return;
    }
    // ---- bucket CSR (256 threads) ----
    int* hist = (int*)fragbuf;
    int* cur  = hist + 512;
    int* pr   = cur + 512;
    int* gpre = pr + 256;
    int b = bid;
    hist[t] = 0; hist[t + 256] = 0;
    gpre[t] = (t < NBKT) ? gcount[t] : 0;
    __syncthreads();
    int sz = gcount[b];
    for (int k = t; k < sz; k += 256)
        atomicAdd(&hist[staging[b * BSTRIDE + k] & 511], 1);
    __syncthreads();
    int a0 = hist[2 * t], a1 = hist[2 * t + 1];
    pr[t] = a0 + a1;
    __syncthreads();
    for (int o = 1; o < 256; o <<= 1) {
        int ad = (t >= o) ? pr[t - o] : 0;
        int gd = (t >= o) ? gpre[t - o] : 0;
        __syncthreads();
        pr[t] += ad;
        gpre[t] += gd;
        __syncthreads();
    }
    int base = gpre[b] - sz;
    int pe = pr[t] - (a0 + a1);
    cur[2 * t] = pe;
    cur[2 * t + 1] = pe + a0;
    int n = (b << BSH) + 2 * t;
    if (n < N_NODES)     off[n]     = base + pe;
    if (n + 1 < N_NODES) off[n + 1] = base + pe + a0;
    if (b == 0 && t == 0) off[N_NODES] = ET;
    __syncthreads();
    for (int k = t; k < sz; k += 256) {
        int p = staging[b * BSTRIDE + k];
        int slot = atomicAdd(&cur[p & 511], 1);
        perm[base + slot] = p >> BSH;
    }
}

// ---------------- standalone LN+GEMM2 (layer 1 + fallback) ----------------

__global__ __launch_bounds__(256) void ln_gemm2_kernel(
        const float* __restrict__ h,
        const float* __restrict__ g, const float* __restrict__ b,
        const ushort* __restrict__ wb, const float* __restrict__ bl,
        const float* __restrict__ br,
        ushort* __restrict__ xlh, ushort* __restrict__ xrh) {
    __shared__ uint4 fragbuf[4 * 272];
    int wid = (blockIdx.x * 256 + threadIdx.x) >> 6;
    int lane = threadIdx.x & 63;
    if (wid >= N_NODES / 16) return;
    uint4* fb = fragbuf + (threadIdx.x >> 6) * 272;
    int q = lane >> 4, m = lane & 15;
    int row0 = wid * 16;
    const float* hrow = h + (size_t)(row0 + m) * FDIM + q * 32;
    float v[32];
#pragma unroll
    for (int i = 0; i < 8; i++) {
        float4 t4 = *(const float4*)&hrow[i * 4];
        v[i * 4 + 0] = t4.x; v[i * 4 + 1] = t4.y; v[i * 4 + 2] = t4.z; v[i * 4 + 3] = t4.w;
    }
    float s = 0.f, ss = 0.f;
#pragma unroll
    for (int i = 0; i < 32; i++) { s += v[i]; ss += v[i] * v[i]; }
    s  += __shfl_xor(s, 16);  s  += __shfl_xor(s, 32);
    ss += __shfl_xor(ss, 16); ss += __shfl_xor(ss, 32);
    float mu = s * (1.f / 128.f);
    float var = ss * (1.f / 128.f) - mu * mu;
    float rv = rsqrtf(var + EPS);
#pragma unroll
    for (int i = 0; i < 8; i++) {
        float4 gv = *(const float4*)&g[q * 32 + i * 4];
        float4 bv = *(const float4*)&b[q * 32 + i * 4];
        v[i * 4 + 0] = (v[i * 4 + 0] - mu) * rv * gv.x + bv.x;
        v[i * 4 + 1] = (v[i * 4 + 1] - mu) * rv * gv.y + bv.y;
        v[i * 4 + 2] = (v[i * 4 + 2] - mu) * rv * gv.z + bv.z;
        v[i * 4 + 3] = (v[i * 4 + 3] - mu) * rv * gv.w + bv.w;
    }
#pragma unroll
    for (int p = 0; p < 4; p++) {
        uint4 u;
        u.x = pk_bf16(v[p * 8 + 0], v[p * 8 + 1]);
        u.y = pk_bf16(v[p * 8 + 2], v[p * 8 + 3]);
        u.z = pk_bf16(v[p * 8 + 4], v[p * 8 + 5]);
        u.w = pk_bf16(v[p * 8 + 6], v[p * 8 + 7]);
        fb[q * 68 + p * 17 + m] = u;
    }
    bf16x8 A[4];
#pragma unroll
    for (int kk = 0; kk < 4; kk++)
        A[kk] = *(const bf16x8*)&fb[kk * 68 + q * 17 + m];
    const bf16x8* wbv = (const bf16x8*)wb;
    f32x4 acc[16];
    f32x4 z = {0.f, 0.f, 0.f, 0.f};
#pragma unroll
    for (int nt = 0; nt < 16; nt++) acc[nt] = z;
#pragma unroll
    for (int nt = 0; nt < 16; nt++) {
#pragma unroll
        for (int kk = 0; kk < 4; kk++) {
            bf16x8 B = wbv[(nt * 4 + kk) * 64 + lane];
            acc[nt] = __builtin_amdgcn_mfma_f32_16x16x32_bf16(A[kk], B, acc[nt], 0, 0, 0);
        }
    }
#pragma unroll
    for (int nt = 0; nt < 16; nt++) {
        int col = nt * 16 + m;
        if (nt < 8) {
            float bias = bl[col];
#pragma unroll
            for (int r = 0; r < 4; r++) {
                _Float16 hf = (_Float16)(acc[nt][r] + bias);
                xlh[(size_t)(row0 + q * 4 + r) * FDIM + col] = __builtin_bit_cast(ushort, hf);
            }
        } else {
            int c2 = col - 128;
            float bias = br[c2];
#pragma unroll
            for (int r = 0; r < 4; r++) {
                _Float16 hf = (_Float16)(acc[nt][r] + bias);
                xrh[(size_t)(row0 + q * 4 + r) * FDIM + c2] = __builtin_bit_cast(ushort, hf);
            }
        }
    }
}

// ---------------- GATv2 aggregation: one wave per TWO nodes ----------------
// Gather path = R6/R8 verified structure (memory-ceiling-pinned, 74.4 µs,
// independent waves — NO post-gather barrier; R10's barrier-coupled L0
// epilogue cost +35 µs from degree variance and is reverted). When
// Wc != nullptr (layer 1) the classification head is fused: WcS preload +
// entry barrier (pre-divergence, free), per-wave hbuf, stride-4 group
// assignment -> sh reads 4-distinct-bank, WcS reads 2-way (free per m136).

__global__ __launch_bounds__(256) void gat_agg_kernel(
        const unsigned* __restrict__ xlp, const unsigned* __restrict__ xrp,
        const int* __restrict__ off, const int* __restrict__ perm,
        const float* __restrict__ att, const float* __restrict__ gb,
        float* __restrict__ h,
        const float* __restrict__ Wc, const float* __restrict__ bc,
        float* __restrict__ out_cls) {
    __shared__ float WcS[FDIM * NK];    // 8 KB
    __shared__ float hbuf[4 * 256];     // 4 KB (2 nodes x 128 per wave)
    bool dofinal = (Wc != nullptr);
    if (dofinal) {
        for (int i = threadIdx.x; i < FDIM * NK; i += 256) WcS[i] = Wc[i];
        __syncthreads();   // uniform: every thread reaches this (no early outs)
    }
    int wave = (blockIdx.x * 256 + threadIdx.x) >> 6;
    unsigned lane = threadIdx.x & 63;
    int iA = wave * 2;
    int iB = iA + 1;   // N even: grid covers exactly N/2 waves
    int2 oA = *(const int2*)&off[iA];
    int eB2 = off[iB + 1];
    h2 xrvA = as_h2(xrp[(unsigned)iA * 64u + lane]);
    h2 xrvB = as_h2(xrp[(unsigned)iB * 64u + lane]);
    const float2 hidA = *(const float2*)&h[(size_t)iA * FDIM + lane * 2];
    const float2 hidB = *(const float2*)&h[(size_t)iB * FDIM + lane * 2];
    const float2 gbv = *(const float2*)&gb[lane * 2];
    float2 attf = *(const float2*)&att[lane * 2];
    h2 attp; attp[0] = (_Float16)(attf.x * 1.44269504f);
    attp[1] = (_Float16)(attf.y * 1.44269504f);
    const h2 c06 = {(_Float16)0.6f, (_Float16)0.6f};
    const h2 c04 = {(_Float16)0.4f, (_Float16)0.4f};
    bool b0 = lane & 1, b1 = lane & 2;
    int begA = __builtin_amdgcn_readfirstlane(oA.x);
    int endA = __builtin_amdgcn_readfirstlane(oA.y);
    int begB = endA;
    int endB = __builtin_amdgcn_readfirstlane(eB2);
    const char* xlB_ = (const char*)xlp;
    unsigned laneB = lane << 2;

#define GLD(J) (*(const unsigned*)(xlB_ + ((unsigned)(J) * 256u + laneB)))

#define EDGE_PARTIAL(XRV, U, T)                                     \
    {                                                               \
        h2 mm = as_h2(U) + XRV;                                     \
        h2 am = as_h2(as_u(mm) & 0x7FFF7FFFu);                      \
        h2 sv = am * c04 + mm * c06;                                \
        T = __builtin_amdgcn_fdot2(sv, attp, 0.f, false);           \
    }

#define COMPUTE4(S, U0, U1, U2, U3)                                 \
    {                                                               \
        float t0, t1, t2, t3;                                       \
        EDGE_PARTIAL(xrv##S, U0, t0);                               \
        EDGE_PARTIAL(xrv##S, U1, t1);                               \
        EDGE_PARTIAL(xrv##S, U2, t2);                               \
        EDGE_PARTIAL(xrv##S, U3, t3);                               \
        float u   = b0 ? t1 : t0;                                   \
        float uu2 = b0 ? t0 : t1;                                   \
        u += DX1(uu2);                                              \
        float vv  = b0 ? t3 : t2;                                   \
        float vv2 = b0 ? t2 : t3;                                   \
        vv += DX1(vv2);                                             \
        float ww  = b1 ? vv : u;                                    \
        float ww2 = b1 ? u : vv;                                    \
        ww += DX2(ww2);                                             \
        ww += DR4(ww);                                              \
        ww += DR8(ww);                                              \
        float ew = exp2_hw(ww);                                     \
        dloc##S += ew;                                              \
        float w0 = DB0(ew);                                         \
        float w1 = DB1(ew);                                         \
        float w2 = DB2(ew);                                         \
        float w3 = DB3(ew);                                         \
        FMAMIX_LO(accx##S, U0, w0); FMAMIX_HI(accy##S, U0, w0);     \
        FMAMIX_LO(accx##S, U1, w1); FMAMIX_HI(accy##S, U1, w1);     \
        FMAMIX_LO(accx##S, U2, w2); FMAMIX_HI(accy##S, U2, w2);     \
        FMAMIX_LO(accx##S, U3, w3); FMAMIX_HI(accy##S, U3, w3);     \
    }

#define TAIL1(S, U)                                                 \
    {                                                               \
        float tt;                                                   \
        EDGE_PARTIAL(xrv##S, U, tt);                                \
        tt += DX1(tt);                                              \
        tt += DX2(tt);                                              \
        tt += DR4(tt);                                              \
        tt += DR8(tt);                                              \
        float w = exp2_hw(tt);                                      \
        if ((lane & 3) == 0) dloc##S += w;                          \
        FMAMIX_LO(accx##S, U, w); FMAMIX_HI(accy##S, U, w);         \
    }

    int nbA = (endA - begA) >> 2, tlA = (endA - begA) & 3;
    int nbB = (endB - begB) >> 2, tlB = (endB - begB) & 3;
    float accxA = 0.f, accyA = 0.f, dlocA = 0.f;
    float accxB = 0.f, accyB = 0.f, dlocB = 0.f;
    unsigned c0A, c1A, c2A, c3A, d0A, d1A, d2A, d3A; int4 p2A;
    unsigned c0B, c1B, c2B, c3B, d0B, d1B, d2B, d3B; int4 p2B;
    unsigned t0A = 0, t1A = 0, t2A = 0, t0B = 0, t1B = 0, t2B = 0;
    int4 p0A, p1A, ptA, p0B, p1B, ptB;

    if (nbA > 0) {
        __builtin_memcpy(&p0A, perm + begA, 16);
        __builtin_memcpy(&p1A, perm + begA + 4, 16);
        __builtin_memcpy(&p2A, perm + begA + 8, 16);
    }
    if (tlA > 0) __builtin_memcpy(&ptA, perm + begA + 4 * nbA, 16);
    if (nbB > 0) {
        __builtin_memcpy(&p0B, perm + begB, 16);
        __builtin_memcpy(&p1B, perm + begB + 4, 16);
        __builtin_memcpy(&p2B, perm + begB + 8, 16);
    }
    if (tlB > 0) __builtin_memcpy(&ptB, perm + begB + 4 * nbB, 16);
    if (nbA > 0) {
        c0A = GLD(rflm(p0A.x)); c1A = GLD(rflm(p0A.y)); c2A = GLD(rflm(p0A.z)); c3A = GLD(rflm(p0A.w));
        d0A = GLD(rflm(p1A.x)); d1A = GLD(rflm(p1A.y)); d2A = GLD(rflm(p1A.z)); d3A = GLD(rflm(p1A.w));
    }
    if (nbB > 0) {
        c0B = GLD(rflm(p0B.x)); c1B = GLD(rflm(p0B.y)); c2B = GLD(rflm(p0B.z)); c3B = GLD(rflm(p0B.w));
        d0B = GLD(rflm(p1B.x)); d1B = GLD(rflm(p1B.y)); d2B = GLD(rflm(p1B.z)); d3B = GLD(rflm(p1B.w));
    }
    if (tlA > 0) {
        t0A = GLD(rflm(ptA.x));
        if (tlA > 1) t1A = GLD(rflm(ptA.y));
        if (tlA > 2) t2A = GLD(rflm(ptA.z));
    }
    if (tlB > 0) {
        t0B = GLD(rflm(ptB.x));
        if (tlB > 1) t1B = GLD(rflm(ptB.y));
        if (tlB > 2) t2B = GLD(rflm(ptB.z));
    }

    int blkA = 0, blkB = 0;
    while (blkA + 2 < nbA && blkB + 2 < nbB) {
        unsigned e0 = GLD(rflm(p2A.x)), e1 = GLD(rflm(p2A.y));
        unsigned e2 = GLD(rflm(p2A.z)), e3 = GLD(rflm(p2A.w));
        unsigned f0 = GLD(rflm(p2B.x)), f1 = GLD(rflm(p2B.y));
        unsigned f2 = GLD(rflm(p2B.z)), f3 = GLD(rflm(p2B.w));
        __builtin_memcpy(&p2A, perm + begA + 4 * blkA + 12, 16);
        __builtin_memcpy(&p2B, perm + begB + 4 * blkB + 12, 16);
        COMPUTE4(A, c0A, c1A, c2A, c3A);
        c0A = d0A; c1A = d1A; c2A = d2A; c3A = d3A;
        d0A = e0; d1A = e1; d2A = e2; d3A = e3;
        COMPUTE4(B, c0B, c1B, c2B, c3B);
        c0B = d0B; c1B = d1B; c2B = d2B; c3B = d3B;
        d0B = f0; d1B = f1; d2B = f2; d3B = f3;
        ++blkA; ++blkB;
    }
    for (; blkA + 2 < nbA; ++blkA) {
        unsigned e0 = GLD(rflm(p2A.x)), e1 = GLD(rflm(p2A.y));
        unsigned e2 = GLD(rflm(p2A.z)), e3 = GLD(rflm(p2A.w));
        __builtin_memcpy(&p2A, perm + begA + 4 * blkA + 12, 16);
        COMPUTE4(A, c0A, c1A, c2A, c3A);
        c0A = d0A; c1A = d1A; c2A = d2A; c3A = d3A;
        d0A = e0; d1A = e1; d2A = e2; d3A = e3;
    }
    for (; blkB + 2 < nbB; ++blkB) {
        unsigned f0 = GLD(rflm(p2B.x)), f1 = GLD(rflm(p2B.y));
        unsigned f2 = GLD(rflm(p2B.z)), f3 = GLD(rflm(p2B.w));
        __builtin_memcpy(&p2B, perm + begB + 4 * blkB + 12, 16);
        COMPUTE4(B, c0B, c1B, c2B, c3B);
        c0B = d0B; c1B = d1B; c2B = d2B; c3B = d3B;
        d0B = f0; d1B = f1; d2B = f2; d3B = f3;
    }
    if (nbA >= 2) {
        COMPUTE4(A, c0A, c1A, c2A, c3A);
        c0A = d0A; c1A = d1A; c2A = d2A; c3A = d3A;
    }
    if (nbB >= 2) {
        COMPUTE4(B, c0B, c1B, c2B, c3B);
        c0B = d0B; c1B = d1B; c2B = d2B; c3B = d3B;
    }
    if (nbA >= 1) COMPUTE4(A, c0A, c1A, c2A, c3A);
    if (nbB >= 1) COMPUTE4(B, c0B, c1B, c2B, c3B);
    if (tlA > 0) {
        TAIL1(A, t0A);
        if (tlA > 1) TAIL1(A, t1A);
        if (tlA > 2) TAIL1(A, t2A);
    }
    if (tlB > 0) {
        TAIL1(B, t0B);
        if (tlB > 1) TAIL1(B, t1B);
        if (tlB > 2) TAIL1(B, t2B);
    }
#undef EDGE_PARTIAL
#undef COMPUTE4
#undef TAIL1
#undef GLD

    float denA = dlocA + DX1(dlocA);
    denA += DX2(denA);
    float invA = 1.f / denA;
    float2 resA;
    resA.x = fmaxf(accxA * invA + gbv.x, 0.f) + hidA.x;
    resA.y = fmaxf(accyA * invA + gbv.y, 0.f) + hidA.y;
    *(float2*)&h[(size_t)iA * FDIM + lane * 2] = resA;
    float denB = dlocB + DX1(dlocB);
    denB += DX2(denB);
    float invB = 1.f / denB;
    float2 resB;
    resB.x = fmaxf(accxB * invB + gbv.x, 0.f) + hidB.x;
    resB.y = fmaxf(accyB * invB + gbv.y, 0.f) + hidB.y;
    *(float2*)&h[(size_t)iB * FDIM + lane * 2] = resB;

    if (dofinal) {
        // classification from fresh rows; stride-4 groups: sh reads hit 4
        // distinct banks, WcS reads 2-way (free).
        float* sh = hbuf + (threadIdx.x >> 6) * 256;
        sh[lane * 2]       = resA.x; sh[lane * 2 + 1]       = resA.y;
        sh[128 + lane * 2] = resB.x; sh[128 + lane * 2 + 1] = resB.y;
        int k = lane & 15, g = lane >> 4;
        float pA = 0.f, pB = 0.f;
#pragma unroll 8
        for (int i = 0; i < 32; ++i) {
            int c = 4 * i + g;
            float wv = WcS[c * NK + k];
            pA = fmaf(sh[c], wv, pA);
            pB = fmaf(sh[128 + c], wv, pB);
        }
        pA += SWZ(pA, 0x401F);          // xor16
        pB += SWZ(pB, 0x401F);
        pA += __shfl_xor(pA, 32);       // xor32
        pB += __shfl_xor(pB, 32);
        if (g == 0) {
            float bk = bc[k];
            out_cls[(size_t)iA * NK + k] = pA + bk;
            out_cls[(size_t)iB * NK + k] = pB + bk;
        }
    }
}

// ---------------- launch ----------------

extern "C" void kernel_launch(void* const* d_in, const int* in_sizes, int n_in,
                              void* d_out, int out_size, void* d_ws, size_t ws_size,
                              hipStream_t stream) {
    const float* x    = (const float*)d_in[0];
    const int*   ei   = (const int*)  d_in[1];
    const float* Wp   = (const float*)d_in[2];
    const float* bp   = (const float*)d_in[3];
    const float* ln_g = (const float*)d_in[4];
    const float* ln_b = (const float*)d_in[5];
    const float* Wl   = (const float*)d_in[6];
    const float* bl   = (const float*)d_in[7];
    const float* Wr   = (const float*)d_in[8];
    const float* br   = (const float*)d_in[9];
    const float* att  = (const float*)d_in[10];
    const float* gb   = (const float*)d_in[11];
    const float* Wc   = (const float*)d_in[12];
    const float* bc   = (const float*)d_in[13];

    float* out_cls = (float*)d_out;
    float* h = out_cls + (size_t)N_NODES * NK;   // second output region doubles as h buffer

    char* w = (char*)d_ws;
    int* off    = (int*)w; w += (size_t)(N_NODES + 1) * sizeof(int);
    int* gcount = (int*)w; w += 256 * sizeof(int);
    int* perm   = (int*)w; w += (size_t)ET * sizeof(int);
    uintptr_t a = ((uintptr_t)w + 255) & ~(uintptr_t)255;
    ushort* xlh = (ushort*)a;                             // [N][128] fp16
    ushort* xrh = xlh + (size_t)N_NODES * FDIM;           // [N][128] fp16
    ushort* wbp = xrh + (size_t)N_NODES * FDIM;             // proj W swizzled (32 KB)
    ushort* wbl0 = wbp + 8 * 4 * 64 * 8;                    // layer0 Wl|Wr (64 KB)
    ushort* wbl1 = wbl0 + 16 * 4 * 64 * 8;                  // layer1
    char* wend = (char*)(wbl1 + 16 * 4 * 64 * 8);
    size_t base_need = (size_t)(wend - (char*)d_ws);
    size_t stag_sz = (size_t)NBKT * BSTRIDE * sizeof(int);
    bool roomy = (ws_size >= base_need + stag_sz);
    int* staging = roomy ? (int*)wend : (int*)xlh;

    // CSR by dst (rebuilt every call — ws is re-poisoned)
    hipMemsetAsync(gcount, 0, NBKT * sizeof(int), stream);
    prep_kernel<<<PART_BLOCKS + 40, 256, 0, stream>>>(
        ei, gcount, staging, Wp, Wl, Wr, wbp, wbl0, wbl1);
    const int gw = (N_NODES / 16 + 3) / 4;   // 1563 proj blocks
    csr_projln_kernel<<<NBKT + gw, 256, 0, stream>>>(
        staging, gcount, off, perm, x, wbp, bp, h,
        roomy ? wbl0 : (const ushort*)nullptr,
        ln_g, ln_b, bl, br, xlh, xrh);
    if (!roomy)
        ln_gemm2_kernel<<<gw, 256, 0, stream>>>(
            h, ln_g, ln_b, wbl0, bl, br, xlh, xrh);

    // layer 0 aggregation (no classification head)
    gat_agg_kernel<<<(N_NODES / 2) / 4, 256, 0, stream>>>(
        (const unsigned*)xlh, (const unsigned*)xrh, off, perm,
        att, gb, h, nullptr, nullptr, nullptr);
    // layer 1 transform + aggregation with fused classification head
    ln_gemm2_kernel<<<gw, 256, 0, stream>>>(
        h, ln_g + FDIM, ln_b + FDIM, wbl1, bl + FDIM, br + FDIM, xlh, xrh);
    gat_agg_kernel<<<(N_NODES / 2) / 4, 256, 0, stream>>>(
        (const unsigned*)xlh, (const unsigned*)xrh, off, perm,
        att + FDIM, gb + FDIM, h, Wc, bc, out_cls);
}